// Round 7
// baseline (555.593 us; speedup 1.0000x reference)
//
#include <hip/hip_runtime.h>
#include <hip/hip_bf16.h>

typedef __bf16 bf16;
typedef __bf16 bf16x4 __attribute__((ext_vector_type(4)));
typedef __bf16 bf16x8 __attribute__((ext_vector_type(8)));
typedef float  f32x4  __attribute__((ext_vector_type(4)));

#define DEVFN static __device__ __forceinline__

static constexpr int T_STEPS = 25;
static constexpr int BATCH   = 256;
static constexpr int MROWS   = T_STEPS * BATCH;  // 6400

// async global->LDS, 16B/lane; LDS base must be wave-uniform (HW adds lane*16).
DEVFN void llds16(const void* g, void* l) {
    __builtin_amdgcn_global_load_lds(
        (const __attribute__((address_space(1))) void*)g,
        (__attribute__((address_space(3))) void*)l, 16, 0, 0);
}

// ---------------------------------------------------------------------------
// fused precision-split kernel: one launch covers w0(3-plane), w1(3-plane),
// w2(2-plane), x(3-plane). Region branch is block-uniform.
DEVFN void split3_chunk(const float* src, bf16* p0, bf16* p1, bf16* p2, int i) {
    float4 v = *(const float4*)(src + i);
    float vv[4] = {v.x, v.y, v.z, v.w};
    bf16x4 a, b, c;
#pragma unroll
    for (int k = 0; k < 4; ++k) {
        bf16 h0 = (bf16)vv[k];
        float r1 = vv[k] - (float)h0;      // exact
        bf16 h1 = (bf16)r1;
        float r2 = r1 - (float)h1;         // exact
        a[k] = h0; b[k] = h1; c[k] = (bf16)r2;
    }
    *(bf16x4*)(p0 + i) = a;
    *(bf16x4*)(p1 + i) = b;
    *(bf16x4*)(p2 + i) = c;
}

DEVFN void split2_chunk(const float* src, bf16* p0, bf16* p1, int i) {
    float4 v = *(const float4*)(src + i);
    float vv[4] = {v.x, v.y, v.z, v.w};
    bf16x4 a, b;
#pragma unroll
    for (int k = 0; k < 4; ++k) {
        bf16 h0 = (bf16)vv[k];
        a[k] = h0; b[k] = (bf16)(vv[k] - (float)h0);
    }
    *(bf16x4*)(p0 + i) = a;
    *(bf16x4*)(p1 + i) = b;
}

// block counts per region (1024 elems per block)
static constexpr int SB_W0 = 2048;   // 2048*1024/1024
static constexpr int SB_W1 = 4096;
static constexpr int SB_W2 = 2048;
static constexpr int SB_X  = 6400;

__global__ void split_all(const float* __restrict__ w0, bf16* w0p0, bf16* w0p1, bf16* w0p2,
                          const float* __restrict__ w1, bf16* w1p0, bf16* w1p1, bf16* w1p2,
                          const float* __restrict__ w2, bf16* w2p0, bf16* w2p1,
                          const float* __restrict__ x,  bf16* xp0,  bf16* xp1,  bf16* xp2) {
    int b = blockIdx.x;
    if (b < SB_W0) {
        split3_chunk(w0, w0p0, w0p1, w0p2, b * 1024 + threadIdx.x * 4);
    } else if (b < SB_W0 + SB_W1) {
        split3_chunk(w1, w1p0, w1p1, w1p2, (b - SB_W0) * 1024 + threadIdx.x * 4);
    } else if (b < SB_W0 + SB_W1 + SB_W2) {
        split2_chunk(w2, w2p0, w2p1, (b - SB_W0 - SB_W1) * 1024 + threadIdx.x * 4);
    } else {
        split3_chunk(x, xp0, xp1, xp2, (b - SB_W0 - SB_W1 - SB_W2) * 1024 + threadIdx.x * 4);
    }
}

// ---------------------------------------------------------------------------
// Tile machinery: BM=BN=128, BK=32, 256 thr = 4 waves (2x2 quadrants of 64x64),
// each wave 4x4 tiles of 16x16x32 bf16 MFMA.
// LDS XOR swizzle (R6-verified: SQ_LDS_BANK_CONFLICT==0, bit-correct):
// 16B chunk q of row r stored at chunk position q ^ ((r>>1)&3).
// XCD-affinity flat-grid swizzle (R7): dispatch round-robins flat%8 across
// XCDs, so map column y from flat%8 -> each XCD owns 1-2 B-columns; its
// 1.6-3.1 MB of weight planes stay L2-resident and staging DMAs become
// L2 hits instead of HBM misses (attacks the vmcnt barrier drain).
struct TileCtx {
    int t, lane, wm, wn, bm, bn, fr, fkS, cr, cc;
};

DEVFN TileCtx make_ctx(int bx, int by) {
    TileCtx x;
    x.t = threadIdx.x; x.lane = x.t & 63;
    int wv = x.t >> 6;
    x.wm = (wv >> 1) * 64; x.wn = (wv & 1) * 64;
    x.bm = bx * 128; x.bn = by * 128;
    x.fr  = x.lane & 15;
    x.fkS = (((x.lane >> 4) ^ ((x.lane >> 1) & 3))) * 16;   // swizzled chunk, bytes
    x.cr = (x.lane >> 4) * 4; x.cc = x.lane & 15;
    return x;
}

// NBY=16: flat in [0,800): h=flat/400, rem=flat%400, y=2*(rem&7)+h, x=rem>>3
// NBY=8 : flat in [0,400): y=flat&7, x=flat>>3
template <int NBY>
DEVFN void grid_swizzle(int flat, int& bx, int& by) {
    if constexpr (NBY == 16) {
        int h   = flat / 400;
        int rem = flat - h * 400;
        by = 2 * (rem & 7) + h;
        bx = rem >> 3;
    } else {
        by = flat & 7;
        bx = flat >> 3;
    }
}

// stage one 128x32 bf16 plane into LDS, swizzled (slot c holds global chunk
// ((c&3) ^ ((c>>3)&3)) of row (c>>2); LDS dest stays lane-contiguous).
DEVFN void stage_plane(const bf16* g, bf16* s, int base_row, int K, int k0, int t) {
#pragma unroll
    for (int r = 0; r < 2; ++r) {
        int c   = t + r * 256;                 // 512 x 16B chunks
        int row = c >> 2;
        int kc  = (((c & 3) ^ ((c >> 3) & 3))) * 8;
        llds16(g + (size_t)(base_row + row) * K + k0 + kc, (bf16*)((char*)s + (c >> 6) * 1024));
    }
}

// swizzled LDS fragment read (A and B operands)
DEVFN void frag4(bf16x8* f, const bf16* s, int wrow, int fr, int fkS) {
#pragma unroll
    for (int i = 0; i < 4; ++i)
        f[i] = *(const bf16x8*)((const char*)s + (wrow + i * 16 + fr) * 64 + fkS);
}

DEVFN void mfma16(f32x4 (&acc)[4][4], const bf16x8* a, const bf16x8* b) {
#pragma unroll
    for (int i = 0; i < 4; ++i)
#pragma unroll
        for (int j = 0; j < 4; ++j)
            acc[i][j] = __builtin_amdgcn_mfma_f32_16x16x32_bf16(a[i], b[j], acc[i][j], 0, 0, 0);
}

// fp64 merge: accM + accS + bias summed in double, single round to f32.
DEVFN void epilogue(const f32x4 (&accM)[4][4], const f32x4 (&accS)[4][4],
                    const float* bias, float* C, int N, const TileCtx& x) {
#pragma unroll
    for (int j = 0; j < 4; ++j) {
        int col   = x.bn + x.wn + j * 16 + x.cc;
        double bv = (double)bias[col];
#pragma unroll
        for (int i = 0; i < 4; ++i) {
            int row0 = x.bm + x.wm + i * 16 + x.cr;
#pragma unroll
            for (int r = 0; r < 4; ++r) {
                double v = (double)accM[i][j][r] + (double)accS[i][j][r] + bv;
                C[(size_t)(row0 + r) * N + col] = (float)v;
            }
        }
    }
}

// ---------------------------------------------------------------------------
// C = A @ (B0+B1[+B2])^T + bias; A is exact bf16 (spikes). WP=3: dual-acc.
template <int WP, int NBY>
__global__ __launch_bounds__(256, 2)
void gemm_sw(const bf16* __restrict__ A, const bf16* __restrict__ B0,
             const bf16* __restrict__ B1, const bf16* __restrict__ B2,
             const float* __restrict__ bias, float* __restrict__ C,
             int M, int N, int K) {
    __shared__ __align__(1024) bf16 sA [128 * 32];
    __shared__ __align__(1024) bf16 sB0[128 * 32];
    __shared__ __align__(1024) bf16 sB1[128 * 32];
    __shared__ __align__(1024) bf16 sB2[(WP == 3) ? 128 * 32 : 64];
    int bx, by; grid_swizzle<NBY>(blockIdx.x, bx, by);
    TileCtx x = make_ctx(bx, by);
    f32x4 accM[4][4] = {}, accS[4][4] = {};

    for (int k0 = 0; k0 < K; k0 += 32) {
        stage_plane(A,  sA,  x.bm, K, k0, x.t);
        stage_plane(B0, sB0, x.bn, K, k0, x.t);
        stage_plane(B1, sB1, x.bn, K, k0, x.t);
        if constexpr (WP == 3) stage_plane(B2, sB2, x.bn, K, k0, x.t);
        __syncthreads();

        bf16x8 a[4], b[4];
        frag4(a, sA, x.wm, x.fr, x.fkS);
        frag4(b, sB0, x.wn, x.fr, x.fkS);
        mfma16(accM, a, b);
        frag4(b, sB1, x.wn, x.fr, x.fkS);
        if constexpr (WP == 3) { mfma16(accS, a, b); } else { mfma16(accM, a, b); }
        if constexpr (WP == 3) { frag4(b, sB2, x.wn, x.fr, x.fkS); mfma16(accS, a, b); }
        __syncthreads();
    }
    epilogue(accM, accS, bias, C, N, x);
}

// ---------------------------------------------------------------------------
// C = (A0+A1+A2) @ (B0+B1+B2)^T + bias; accM = main (A0*B0), accS = the five
// O(2^-9..2^-18) correction passes. Dropped cross-terms are O(2^-27).
__global__ __launch_bounds__(256, 2)
void gemm_x3w3(const bf16* __restrict__ A0, const bf16* __restrict__ A1,
               const bf16* __restrict__ A2, const bf16* __restrict__ B0,
               const bf16* __restrict__ B1, const bf16* __restrict__ B2,
               const float* __restrict__ bias, float* __restrict__ C,
               int M, int N, int K) {
    __shared__ __align__(1024) bf16 sA0[128 * 32];
    __shared__ __align__(1024) bf16 sA1[128 * 32];
    __shared__ __align__(1024) bf16 sA2[128 * 32];
    __shared__ __align__(1024) bf16 sB0[128 * 32];
    __shared__ __align__(1024) bf16 sB1[128 * 32];
    __shared__ __align__(1024) bf16 sB2[128 * 32];
    int bx, by; grid_swizzle<16>(blockIdx.x, bx, by);
    TileCtx x = make_ctx(bx, by);
    f32x4 accM[4][4] = {}, accS[4][4] = {};

    for (int k0 = 0; k0 < K; k0 += 32) {
        stage_plane(A0, sA0, x.bm, K, k0, x.t);
        stage_plane(A1, sA1, x.bm, K, k0, x.t);
        stage_plane(A2, sA2, x.bm, K, k0, x.t);
        stage_plane(B0, sB0, x.bn, K, k0, x.t);
        stage_plane(B1, sB1, x.bn, K, k0, x.t);
        stage_plane(B2, sB2, x.bn, K, k0, x.t);
        __syncthreads();

        bf16x8 b0[4], b1[4], b2[4], a[4];
        frag4(b0, sB0, x.wn, x.fr, x.fkS);
        frag4(b1, sB1, x.wn, x.fr, x.fkS);
        frag4(b2, sB2, x.wn, x.fr, x.fkS);
        frag4(a, sA0, x.wm, x.fr, x.fkS);
        mfma16(accM, a, b0);            // main
        mfma16(accS, a, b1);
        mfma16(accS, a, b2);
        frag4(a, sA1, x.wm, x.fr, x.fkS);
        mfma16(accS, a, b0);
        mfma16(accS, a, b1);
        frag4(a, sA2, x.wm, x.fr, x.fkS);
        mfma16(accS, a, b0);
        __syncthreads();
    }
    epilogue(accM, accS, bias, C, N, x);
}

// ---------------------------------------------------------------------------
// LIF scans — fp64 recurrence (R4-verified: kills the f32 drift flips).
template <int F>
__global__ void lif_hidden(const float* __restrict__ cur, bf16* __restrict__ spk) {
    const int tid = blockIdx.x * 256 + threadIdx.x;  // b*F + f
    double m = 0.0;
    size_t off = tid;
#pragma unroll
    for (int t = 0; t < T_STEPS; ++t) {
        m = 0.9 * m + (double)cur[off];
        bool s = (m - 1.0) > 0.0;
        spk[off] = (bf16)(s ? 1.0f : 0.0f);
        if (s) m -= 1.0;
        off += (size_t)BATCH * F;
    }
}

__global__ void lif_out(const float* __restrict__ cur, float* __restrict__ out) {
    const int tid = blockIdx.x * 256 + threadIdx.x;  // b*1024 + f
    double m = 0.0;
    size_t off = tid;
#pragma unroll
    for (int t = 0; t < T_STEPS; ++t) {
        m = 0.9 * m + (double)cur[off];
        bool s = (m - 1.0) > 0.0;
        out[off] = s ? 1.0f : 0.0f;
        if (s) m -= 1.0;
        off += (size_t)BATCH * 1024;
    }
    out[(size_t)T_STEPS * BATCH * 1024 + tid] = (float)m;  // final membrane (output 1)
}

// ---------------------------------------------------------------------------
extern "C" void kernel_launch(void* const* d_in, const int* in_sizes, int n_in,
                              void* d_out, int out_size, void* d_ws, size_t ws_size,
                              hipStream_t stream) {
    const float* xin = (const float*)d_in[0];
    const float* w0  = (const float*)d_in[1];
    const float* b0  = (const float*)d_in[2];
    const float* w1  = (const float*)d_in[3];
    const float* b1  = (const float*)d_in[4];
    const float* w2  = (const float*)d_in[5];
    const float* b2  = (const float*)d_in[6];
    float* out = (float*)d_out;

    constexpr size_t NW0 = 2048 * 1024;
    constexpr size_t NW1 = 2048 * 2048;
    constexpr size_t NW2 = 1024 * 2048;
    constexpr size_t NX  = (size_t)MROWS * 1024;  // 6,553,600
    constexpr size_t NH  = (size_t)MROWS * 2048;  // 13,107,200

    char* ws = (char*)d_ws;
    size_t off = 0;
    auto carve = [&](size_t bytes) { char* p = ws + off; off += bytes; return p; };

    // long-lived planes
    bf16* w1p0 = (bf16*)carve(NW1 * 2);
    bf16* w1p1 = (bf16*)carve(NW1 * 2);
    bf16* w1p2 = (bf16*)carve(NW1 * 2);
    bf16* w2p0 = (bf16*)carve(NW2 * 2);
    bf16* w2p1 = (bf16*)carve(NW2 * 2);
    // pool: w0 planes + x planes live only until G0; s0/s1 overlay afterwards
    char* pool = carve(2 * NH * 2);          // 52,428,800 B
    bf16* w0p0 = (bf16*)pool;
    bf16* w0p1 = w0p0 + NW0;
    bf16* w0p2 = w0p1 + NW0;
    bf16* xp0  = w0p2 + NW0;
    bf16* xp1  = xp0 + NX;
    bf16* xp2  = xp1 + NX;                   // ends at pool + 51,904,512
    bf16* s0   = (bf16*)pool;                // written after G0 consumed w0/x
    bf16* s1   = s0 + NH;                    // written after G1 consumed s0
    float* cur = (float*)carve(NH * 4);
    if (ws_size < off) return;               // 138,412,032 B total

    // 1) fused precision splits (one launch)
    split_all<<<SB_W0 + SB_W1 + SB_W2 + SB_X, 256, 0, stream>>>(
        w0, w0p0, w0p1, w0p2, w1, w1p0, w1p1, w1p2,
        w2, w2p0, w2p1, xin, xp0, xp1, xp2);

    // 2) layer 0: cur0 = x @ W0^T + b0 (M=6400,N=2048,K=1024; 6-pass dual-acc)
    gemm_x3w3<<<800, 256, 0, stream>>>(xp0, xp1, xp2, w0p0, w0p1, w0p2,
                                       b0, cur, MROWS, 2048, 1024);
    lif_hidden<2048><<<(BATCH * 2048) / 256, 256, 0, stream>>>(cur, s0);

    // 3) layer 1: cur1 = s0 @ W1^T + b1 (K=2048; 3-pass dual-acc)
    gemm_sw<3, 16><<<800, 256, 0, stream>>>(s0, w1p0, w1p1, w1p2,
                                            b1, cur, MROWS, 2048, 2048);
    lif_hidden<2048><<<(BATCH * 2048) / 256, 256, 0, stream>>>(cur, s1);

    // 4) layer 2: cur2 = s1 @ W2^T + b2 (N=1024; 2-pass, loose budget)
    gemm_sw<2, 8><<<400, 256, 0, stream>>>(s1, w2p0, w2p1, nullptr,
                                           b2, cur, MROWS, 1024, 2048);
    lif_out<<<(BATCH * 1024) / 256, 256, 0, stream>>>(cur, out);
}

// Round 9
// 534.114 us; speedup vs baseline: 1.0402x; 1.0402x over previous
//
#include <hip/hip_runtime.h>
#include <hip/hip_bf16.h>

typedef __bf16 bf16;
typedef __bf16 bf16x4 __attribute__((ext_vector_type(4)));
typedef __bf16 bf16x8 __attribute__((ext_vector_type(8)));
typedef float  f32x4  __attribute__((ext_vector_type(4)));

#define DEVFN static __device__ __forceinline__

static constexpr int T_STEPS = 25;
static constexpr int BATCH   = 256;
static constexpr int MROWS   = T_STEPS * BATCH;  // 6400

// async global->LDS, 16B/lane; LDS base must be wave-uniform (HW adds lane*16).
DEVFN void llds16(const void* g, void* l) {
    __builtin_amdgcn_global_load_lds(
        (const __attribute__((address_space(1))) void*)g,
        (__attribute__((address_space(3))) void*)l, 16, 0, 0);
}

// ---------------------------------------------------------------------------
// Precision splits. R1/R3/R4/R8 margin evidence: hidden-layer spike margins
// are ~1e-7, so G0/G1 weights and x need 3 bf16 planes (residual 2^-26);
// w2 needs only 2 (layer-2 membranes sit ~0.4 below threshold).
DEVFN void split3_chunk(const float* src, bf16* p0, bf16* p1, bf16* p2, int i) {
    float4 v = *(const float4*)(src + i);
    float vv[4] = {v.x, v.y, v.z, v.w};
    bf16x4 a, b, c;
#pragma unroll
    for (int k = 0; k < 4; ++k) {
        bf16 h0 = (bf16)vv[k];
        float r1 = vv[k] - (float)h0;      // exact
        bf16 h1 = (bf16)r1;
        float r2 = r1 - (float)h1;         // exact
        a[k] = h0; b[k] = h1; c[k] = (bf16)r2;
    }
    *(bf16x4*)(p0 + i) = a;
    *(bf16x4*)(p1 + i) = b;
    *(bf16x4*)(p2 + i) = c;
}

DEVFN void split2_chunk(const float* src, bf16* p0, bf16* p1, int i) {
    float4 v = *(const float4*)(src + i);
    float vv[4] = {v.x, v.y, v.z, v.w};
    bf16x4 a, b;
#pragma unroll
    for (int k = 0; k < 4; ++k) {
        bf16 h0 = (bf16)vv[k];
        a[k] = h0; b[k] = (bf16)(vv[k] - (float)h0);
    }
    *(bf16x4*)(p0 + i) = a;
    *(bf16x4*)(p1 + i) = b;
}

// block counts per region (1024 elems per block)
static constexpr int SB_W0 = 2048;
static constexpr int SB_W1 = 4096;
static constexpr int SB_W2 = 2048;
static constexpr int SB_X  = 6400;

__global__ void split_all(const float* __restrict__ w0, bf16* w0p0, bf16* w0p1, bf16* w0p2,
                          const float* __restrict__ w1, bf16* w1p0, bf16* w1p1, bf16* w1p2,
                          const float* __restrict__ w2, bf16* w2p0, bf16* w2p1,
                          const float* __restrict__ x,  bf16* xp0,  bf16* xp1,  bf16* xp2) {
    int b = blockIdx.x;
    if (b < SB_W0) {
        split3_chunk(w0, w0p0, w0p1, w0p2, b * 1024 + threadIdx.x * 4);
    } else if (b < SB_W0 + SB_W1) {
        split3_chunk(w1, w1p0, w1p1, w1p2, (b - SB_W0) * 1024 + threadIdx.x * 4);
    } else if (b < SB_W0 + SB_W1 + SB_W2) {
        split2_chunk(w2, w2p0, w2p1, (b - SB_W0 - SB_W1) * 1024 + threadIdx.x * 4);
    } else {
        split3_chunk(x, xp0, xp1, xp2, (b - SB_W0 - SB_W1 - SB_W2) * 1024 + threadIdx.x * 4);
    }
}

// ---------------------------------------------------------------------------
// Tile machinery: BM=BN=128, BK=32, 256 thr = 4 waves (2x2 quadrants of 64x64),
// each wave 4x4 tiles of 16x16x32 bf16 MFMA.
// LDS XOR swizzle (R6-verified: SQ_LDS_BANK_CONFLICT==0, bit-correct):
// 16B chunk q of row r stored at chunk position q ^ ((r>>1)&3).
// Plain dim3 grid (R7's XCD swizzle regressed — reverted for good).
struct TileCtx {
    int t, lane, wm, wn, bm, bn, fr, fkS, cr, cc;
};

DEVFN TileCtx make_ctx() {
    TileCtx x;
    x.t = threadIdx.x; x.lane = x.t & 63;
    int wv = x.t >> 6;
    x.wm = (wv >> 1) * 64; x.wn = (wv & 1) * 64;
    x.bm = blockIdx.x * 128; x.bn = blockIdx.y * 128;
    x.fr  = x.lane & 15;
    x.fkS = (((x.lane >> 4) ^ ((x.lane >> 1) & 3))) * 16;   // swizzled chunk, bytes
    x.cr = (x.lane >> 4) * 4; x.cc = x.lane & 15;
    return x;
}

// stage one 128x32 bf16 plane into LDS, swizzled (slot c holds global chunk
// ((c&3) ^ ((c>>3)&3)) of row (c>>2); LDS dest stays lane-contiguous).
DEVFN void stage_plane(const bf16* g, bf16* s, int base_row, int K, int k0, int t) {
#pragma unroll
    for (int r = 0; r < 2; ++r) {
        int c   = t + r * 256;                 // 512 x 16B chunks
        int row = c >> 2;
        int kc  = (((c & 3) ^ ((c >> 3) & 3))) * 8;
        llds16(g + (size_t)(base_row + row) * K + k0 + kc, (bf16*)((char*)s + (c >> 6) * 1024));
    }
}

// swizzled LDS fragment read (A and B operands)
DEVFN void frag4(bf16x8* f, const bf16* s, int wrow, int fr, int fkS) {
#pragma unroll
    for (int i = 0; i < 4; ++i)
        f[i] = *(const bf16x8*)((const char*)s + (wrow + i * 16 + fr) * 64 + fkS);
}

DEVFN void mfma16(f32x4 (&acc)[4][4], const bf16x8* a, const bf16x8* b) {
#pragma unroll
    for (int i = 0; i < 4; ++i)
#pragma unroll
        for (int j = 0; j < 4; ++j)
            acc[i][j] = __builtin_amdgcn_mfma_f32_16x16x32_bf16(a[i], b[j], acc[i][j], 0, 0, 0);
}

// fp64 merge: accM + accS + bias summed in double, single round to f32.
DEVFN void epilogue(const f32x4 (&accM)[4][4], const f32x4 (&accS)[4][4],
                    const float* bias, float* C, int N, const TileCtx& x) {
#pragma unroll
    for (int j = 0; j < 4; ++j) {
        int col   = x.bn + x.wn + j * 16 + x.cc;
        double bv = (double)bias[col];
#pragma unroll
        for (int i = 0; i < 4; ++i) {
            int row0 = x.bm + x.wm + i * 16 + x.cr;
#pragma unroll
            for (int r = 0; r < 4; ++r) {
                double v = (double)accM[i][j][r] + (double)accS[i][j][r] + bv;
                C[(size_t)(row0 + r) * N + col] = (float)v;
            }
        }
    }
}

// ---------------------------------------------------------------------------
// C = A @ (B0+B1[+B2])^T + bias; A is exact bf16 (spikes). WP=3: dual-acc.
template <int WP>
__global__ __launch_bounds__(256, 2)
void gemm_sw(const bf16* __restrict__ A, const bf16* __restrict__ B0,
             const bf16* __restrict__ B1, const bf16* __restrict__ B2,
             const float* __restrict__ bias, float* __restrict__ C,
             int M, int N, int K) {
    __shared__ __align__(1024) bf16 sA [128 * 32];
    __shared__ __align__(1024) bf16 sB0[128 * 32];
    __shared__ __align__(1024) bf16 sB1[128 * 32];
    __shared__ __align__(1024) bf16 sB2[(WP == 3) ? 128 * 32 : 64];
    TileCtx x = make_ctx();
    f32x4 accM[4][4] = {}, accS[4][4] = {};

    for (int k0 = 0; k0 < K; k0 += 32) {
        stage_plane(A,  sA,  x.bm, K, k0, x.t);
        stage_plane(B0, sB0, x.bn, K, k0, x.t);
        stage_plane(B1, sB1, x.bn, K, k0, x.t);
        if constexpr (WP == 3) stage_plane(B2, sB2, x.bn, K, k0, x.t);
        __syncthreads();

        bf16x8 a[4], b[4];
        frag4(a, sA, x.wm, x.fr, x.fkS);
        frag4(b, sB0, x.wn, x.fr, x.fkS);
        mfma16(accM, a, b);
        frag4(b, sB1, x.wn, x.fr, x.fkS);
        if constexpr (WP == 3) { mfma16(accS, a, b); } else { mfma16(accM, a, b); }
        if constexpr (WP == 3) { frag4(b, sB2, x.wn, x.fr, x.fkS); mfma16(accS, a, b); }
        __syncthreads();
    }
    epilogue(accM, accS, bias, C, N, x);
}

// ---------------------------------------------------------------------------
// C = (A0+A1+A2) @ (B0+B1+B2)^T + bias; accM = main (A0*B0), accS = the five
// O(2^-9..2^-18) correction passes. Dropped cross-terms are O(2^-27).
// R8 margin analysis: all six kept passes are REQUIRED (~1e-7 spike margins).
__global__ __launch_bounds__(256, 2)
void gemm_x3w3(const bf16* __restrict__ A0, const bf16* __restrict__ A1,
               const bf16* __restrict__ A2, const bf16* __restrict__ B0,
               const bf16* __restrict__ B1, const bf16* __restrict__ B2,
               const float* __restrict__ bias, float* __restrict__ C,
               int M, int N, int K) {
    __shared__ __align__(1024) bf16 sA0[128 * 32];
    __shared__ __align__(1024) bf16 sA1[128 * 32];
    __shared__ __align__(1024) bf16 sA2[128 * 32];
    __shared__ __align__(1024) bf16 sB0[128 * 32];
    __shared__ __align__(1024) bf16 sB1[128 * 32];
    __shared__ __align__(1024) bf16 sB2[128 * 32];
    TileCtx x = make_ctx();
    f32x4 accM[4][4] = {}, accS[4][4] = {};

    for (int k0 = 0; k0 < K; k0 += 32) {
        stage_plane(A0, sA0, x.bm, K, k0, x.t);
        stage_plane(A1, sA1, x.bm, K, k0, x.t);
        stage_plane(A2, sA2, x.bm, K, k0, x.t);
        stage_plane(B0, sB0, x.bn, K, k0, x.t);
        stage_plane(B1, sB1, x.bn, K, k0, x.t);
        stage_plane(B2, sB2, x.bn, K, k0, x.t);
        __syncthreads();

        bf16x8 b0[4], b1[4], b2[4], a[4];
        frag4(b0, sB0, x.wn, x.fr, x.fkS);
        frag4(b1, sB1, x.wn, x.fr, x.fkS);
        frag4(b2, sB2, x.wn, x.fr, x.fkS);
        frag4(a, sA0, x.wm, x.fr, x.fkS);
        mfma16(accM, a, b0);            // main
        mfma16(accS, a, b1);
        mfma16(accS, a, b2);
        frag4(a, sA1, x.wm, x.fr, x.fkS);
        mfma16(accS, a, b0);
        mfma16(accS, a, b1);
        frag4(a, sA2, x.wm, x.fr, x.fkS);
        mfma16(accS, a, b0);
        __syncthreads();
    }
    epilogue(accM, accS, bias, C, N, x);
}

// ---------------------------------------------------------------------------
// LIF scans — fp64 recurrence (R4-verified: kills the f32 drift flips).
template <int F>
__global__ void lif_hidden(const float* __restrict__ cur, bf16* __restrict__ spk) {
    const int tid = blockIdx.x * 256 + threadIdx.x;  // b*F + f
    double m = 0.0;
    size_t off = tid;
#pragma unroll
    for (int t = 0; t < T_STEPS; ++t) {
        m = 0.9 * m + (double)cur[off];
        bool s = (m - 1.0) > 0.0;
        spk[off] = (bf16)(s ? 1.0f : 0.0f);
        if (s) m -= 1.0;
        off += (size_t)BATCH * F;
    }
}

__global__ void lif_out(const float* __restrict__ cur, float* __restrict__ out) {
    const int tid = blockIdx.x * 256 + threadIdx.x;  // b*1024 + f
    double m = 0.0;
    size_t off = tid;
#pragma unroll
    for (int t = 0; t < T_STEPS; ++t) {
        m = 0.9 * m + (double)cur[off];
        bool s = (m - 1.0) > 0.0;
        out[off] = s ? 1.0f : 0.0f;
        if (s) m -= 1.0;
        off += (size_t)BATCH * 1024;
    }
    out[(size_t)T_STEPS * BATCH * 1024 + tid] = (float)m;  // final membrane (output 1)
}

// ---------------------------------------------------------------------------
extern "C" void kernel_launch(void* const* d_in, const int* in_sizes, int n_in,
                              void* d_out, int out_size, void* d_ws, size_t ws_size,
                              hipStream_t stream) {
    const float* xin = (const float*)d_in[0];
    const float* w0  = (const float*)d_in[1];
    const float* b0  = (const float*)d_in[2];
    const float* w1  = (const float*)d_in[3];
    const float* b1  = (const float*)d_in[4];
    const float* w2  = (const float*)d_in[5];
    const float* b2  = (const float*)d_in[6];
    float* out = (float*)d_out;

    constexpr size_t NW0 = 2048 * 1024;
    constexpr size_t NW1 = 2048 * 2048;
    constexpr size_t NW2 = 1024 * 2048;
    constexpr size_t NX  = (size_t)MROWS * 1024;  // 6,553,600
    constexpr size_t NH  = (size_t)MROWS * 2048;  // 13,107,200

    char* ws = (char*)d_ws;
    size_t off = 0;
    auto carve = [&](size_t bytes) { char* p = ws + off; off += bytes; return p; };

    // long-lived planes
    bf16* w1p0 = (bf16*)carve(NW1 * 2);
    bf16* w1p1 = (bf16*)carve(NW1 * 2);
    bf16* w1p2 = (bf16*)carve(NW1 * 2);
    bf16* w2p0 = (bf16*)carve(NW2 * 2);
    bf16* w2p1 = (bf16*)carve(NW2 * 2);
    // pool: w0 planes + x planes live only until G0; s0/s1 overlay afterwards
    char* pool = carve(2 * NH * 2);          // 52,428,800 B
    bf16* w0p0 = (bf16*)pool;
    bf16* w0p1 = w0p0 + NW0;
    bf16* w0p2 = w0p1 + NW0;
    bf16* xp0  = w0p2 + NW0;
    bf16* xp1  = xp0 + NX;
    bf16* xp2  = xp1 + NX;                   // ends at pool + 51,904,512
    bf16* s0   = (bf16*)pool;                // written after G0 consumed w0/x
    bf16* s1   = s0 + NH;                    // written after G1 consumed s0
    float* cur = (float*)carve(NH * 4);
    if (ws_size < off) return;               // 138,412,032 B total

    // 1) fused precision splits (one launch)
    split_all<<<SB_W0 + SB_W1 + SB_W2 + SB_X, 256, 0, stream>>>(
        w0, w0p0, w0p1, w0p2, w1, w1p0, w1p1, w1p2,
        w2, w2p0, w2p1, xin, xp0, xp1, xp2);

    // 2) layer 0: cur0 = x @ W0^T + b0 (M=6400,N=2048,K=1024; 6-pass dual-acc)
    gemm_x3w3<<<dim3(50, 16), 256, 0, stream>>>(xp0, xp1, xp2, w0p0, w0p1, w0p2,
                                                b0, cur, MROWS, 2048, 1024);
    lif_hidden<2048><<<(BATCH * 2048) / 256, 256, 0, stream>>>(cur, s0);

    // 3) layer 1: cur1 = s0 @ W1^T + b1 (K=2048; 3-pass dual-acc)
    gemm_sw<3><<<dim3(50, 16), 256, 0, stream>>>(s0, w1p0, w1p1, w1p2,
                                                 b1, cur, MROWS, 2048, 2048);
    lif_hidden<2048><<<(BATCH * 2048) / 256, 256, 0, stream>>>(cur, s1);

    // 4) layer 2: cur2 = s1 @ W2^T + b2 (N=1024; 2-pass, R4-verified budget)
    gemm_sw<2><<<dim3(50, 8), 256, 0, stream>>>(s1, w2p0, w2p1, nullptr,
                                                b2, cur, MROWS, 1024, 2048);
    lif_out<<<(BATCH * 1024) / 256, 256, 0, stream>>>(cur, out);
}